// Round 8
// baseline (107.636 us; speedup 1.0000x reference)
//
#include <hip/hip_runtime.h>

// Fused 3-level B3-spline UWT, fp32. x:(16,1024,1024)->out:(16,4,1024,1024)=[w1,w2,w3,c3].
// 64x64 tile. Phases:
//  1: global -> xs (92x96, XOR-swizzled, coalesced)           barrier
//  2: xs -> F[48] registers (per passA item)                  barrier
//  3: horizontal a-trous cascade h1->h2->h3 in F; write u1/u2/u3 into an LDS
//     arena ALIASED over the dead xs (62.7 KB total -> 2 blocks/CU)  barrier
//  4: waves 0-3: vertical 5/13/29-tap from u1/u2/u3 -> w2,w3,c3 (4-row strips)
//     waves 4-5: vertical 5-tap from u1 + x re-read -> w1 (8-row strips)
// u pitch 68 floats (17 f4-slots, 17 mod 8 = 1) -> uniform bank quartets for
// both the strided phase-3 writes and the phase-4 strip reads.

typedef float f4v __attribute__((ext_vector_type(4)));

constexpr int TB   = 384;
constexpr int TCOL = 64;
constexpr int TROW = 64;
constexpr int VH   = 14;          // vertical halo
constexpr int XR   = 92;
constexpr int XP   = 96;          // xs pitch (floats)
constexpr int UP   = 68;          // u pitch (floats)
constexpr int U1R  = 68;          // u1 rows: frame [12,80)
constexpr int U2R  = 76;          // u2 rows: frame [8,84)
constexpr int U3R  = 92;          // u3 rows: frame [0,92)
constexpr int ARENA = (U1R + U2R + U3R) * UP;   // 16048 floats = 62.7 KB
constexpr int HW   = 1024 * 1024;

__device__ constexpr float K13[13] = {
    1.f/256, 4.f/256, 10.f/256, 20.f/256, 31.f/256, 40.f/256, 44.f/256,
    40.f/256, 31.f/256, 20.f/256, 10.f/256, 4.f/256, 1.f/256};
__device__ constexpr float K29[29] = {
    1.f/4096,   4.f/4096,  10.f/4096,  20.f/4096,  35.f/4096,  56.f/4096,
    84.f/4096, 120.f/4096, 161.f/4096, 204.f/4096, 246.f/4096, 284.f/4096,
    315.f/4096, 336.f/4096, 344.f/4096, 336.f/4096, 315.f/4096, 284.f/4096,
    246.f/4096, 204.f/4096, 161.f/4096, 120.f/4096,  84.f/4096,  56.f/4096,
    35.f/4096,  20.f/4096,  10.f/4096,   4.f/4096,   1.f/4096};

__device__ __forceinline__ int refl(int i) {
    return i < 0 ? -i : (i >= 1024 ? 2046 - i : i);
}
// xs: row-major, f4-granular XOR swizzle (uniform banks for row-span reads).
__device__ __forceinline__ int xidx(int r, int c4) { return r * XP + 4 * (c4 ^ (r & 7)); }

__global__ __launch_bounds__(TB, 3)
void uwt3_kernel(const float* __restrict__ x, float* __restrict__ out)
{
    __shared__ float lds[ARENA];
    float* xs  = lds;                         // phases 1-2 (8832 floats)
    float* u1s = lds;                         // phases 3-4, aliases xs
    float* u2s = lds + U1R * UP;
    float* u3s = lds + (U1R + U2R) * UP;

    const int tid = threadIdx.x;

    // bijective XCD chunk swizzle (4096 % 8 == 0)
    const int flat = blockIdx.x;
    const int swz  = (flat & 7) * 512 + (flat >> 3);
    const int bxi = swz & 15;
    const int byi = (swz >> 4) & 15;
    const int bz  = swz >> 8;
    const int bx = bxi * TCOL;
    const int by = byi * TROW;

    const float* xp = x + (size_t)bz * HW;
    float* op = out + (size_t)bz * 4 * HW;

    // ---- phase 1: stage x tile rows [by-14,by+78), cols [bx-16,bx+80) ----
    if (bxi != 0 && bxi != 15) {
        for (int e = tid; e < XR * 24; e += TB) {
            const int r = e / 24, m = e - r * 24;
            const int gr = refl(by - VH + r);
            const f4v v = *(const f4v*)(xp + (size_t)gr * 1024 + (bx - 16 + 4 * m));
            *(f4v*)(xs + xidx(r, m)) = v;
        }
    } else {
        for (int e = tid; e < XR * 96; e += TB) {
            const int r = e / 96, c = e - r * 96;
            const int gr = refl(by - VH + r);
            const int gc = refl(bx - 16 + c);
            xs[xidx(r, c >> 2) + (c & 3)] = xp[(size_t)gr * 1024 + gc];
        }
    }
    __syncthreads();

    // ---- phase 2: xs -> registers (all reads complete before aliasing) ----
    const int gi = tid & 3;          // 16-col group
    const int rp = tid >> 2;         // tile-frame row
    float F[48];
    if (tid < XR * 4) {
#pragma unroll
        for (int m = 0; m < 12; ++m)
            *(f4v*)&F[4 * m] = *(const f4v*)(xs + xidx(rp, 4 * gi + m));
    }
    __syncthreads();

    // ---- phase 3: horizontal cascade, write u1/u2/u3 over dead xs ----
    if (tid < XR * 4) {
        // h1 (d=1): F[i] <- h1 @ x-col i+2
#pragma unroll
        for (int i = 2; i < 42; ++i)
            F[i] = 0.0625f * (F[i] + F[i + 4]) + 0.25f * (F[i + 1] + F[i + 3])
                 + 0.375f * F[i + 2];
        if (rp >= 12 && rp < 80) {          // u1 = h1 center, F[14..30)
            float* d = u1s + (rp - 12) * UP + 16 * gi;
#pragma unroll
            for (int k = 0; k < 4; ++k) {
                const f4v v = {F[14 + 4*k], F[15 + 4*k], F[16 + 4*k], F[17 + 4*k]};
                *(f4v*)(d + 4 * k) = v;
            }
        }
        // h2 (d=2): F[i] <- h2 @ x-col i+6
#pragma unroll
        for (int i = 2; i < 34; ++i)
            F[i] = 0.0625f * (F[i] + F[i + 8]) + 0.25f * (F[i + 2] + F[i + 6])
                 + 0.375f * F[i + 4];
        if (rp >= 8 && rp < 84) {           // u2 = h2 center, F[10..26)
            float* d = u2s + (rp - 8) * UP + 16 * gi;
#pragma unroll
            for (int k = 0; k < 4; ++k) {
                const f4v v = {F[10 + 4*k], F[11 + 4*k], F[12 + 4*k], F[13 + 4*k]};
                *(f4v*)(d + 4 * k) = v;
            }
        }
        // h3 (d=4): F[i] <- h3 @ x-col i+14
#pragma unroll
        for (int i = 2; i < 18; ++i)
            F[i] = 0.0625f * (F[i] + F[i + 16]) + 0.25f * (F[i + 4] + F[i + 12])
                 + 0.375f * F[i + 8];
        {                                   // u3 = h3, F[2..18), all rows
            float* d = u3s + rp * UP + 16 * gi;
#pragma unroll
            for (int k = 0; k < 4; ++k) {
                const f4v v = {F[2 + 4*k], F[3 + 4*k], F[4 + 4*k], F[5 + 4*k]};
                *(f4v*)(d + 4 * k) = v;
            }
        }
    }
    __syncthreads();

    // ---- phase 4: vertical convs + outputs ----
    if (tid < 256) {
        // waves 0-3: w2, w3, c3 on 4-row strips
        const int fc = tid & 15;
        const int r0 = (tid >> 4) * 4;
        const size_t gbase = (size_t)(by + r0) * 1024 + bx + 4 * fc;

        // c1 = V1 u1 (5-tap)
        f4v u1r[8];
#pragma unroll
        for (int i = 0; i < 8; ++i)
            u1r[i] = *(const f4v*)(u1s + (r0 + i) * UP + 4 * fc);
        f4v c1[4];
#pragma unroll
        for (int j = 0; j < 4; ++j)
            c1[j] = 0.0625f * (u1r[j] + u1r[j + 4]) + 0.25f * (u1r[j + 1] + u1r[j + 3])
                  + 0.375f * u1r[j + 2];

        // c2 = V2 u2 (13-tap)
        f4v c2[4] = {{0,0,0,0},{0,0,0,0},{0,0,0,0},{0,0,0,0}};
#pragma unroll
        for (int i = 0; i < 16; ++i) {
            const f4v v = *(const f4v*)(u2s + (r0 + i) * UP + 4 * fc);
#pragma unroll
            for (int j = 0; j < 4; ++j) {
                const int m = i - j;
                if (m >= 0 && m <= 12) c2[j] += K13[m] * v;
            }
        }
#pragma unroll
        for (int j = 0; j < 4; ++j)
            __builtin_nontemporal_store(c1[j] - c2[j],
                (f4v*)(op + 1 * HW + gbase + (size_t)j * 1024));

        // c3 = V3 u3 (29-tap)
        f4v c3[4] = {{0,0,0,0},{0,0,0,0},{0,0,0,0},{0,0,0,0}};
#pragma unroll
        for (int i = 0; i < 32; ++i) {
            const f4v v = *(const f4v*)(u3s + (r0 + i) * UP + 4 * fc);
#pragma unroll
            for (int j = 0; j < 4; ++j) {
                const int m = i - j;
                if (m >= 0 && m <= 28) c3[j] += K29[m] * v;
            }
        }
#pragma unroll
        for (int j = 0; j < 4; ++j) {
            __builtin_nontemporal_store(c2[j] - c3[j],
                (f4v*)(op + 2 * HW + gbase + (size_t)j * 1024));
            __builtin_nontemporal_store(c3[j],
                (f4v*)(op + 3 * HW + gbase + (size_t)j * 1024));
        }
    } else {
        // waves 4-5: w1 = x - V1 u1 on 8-row strips (x re-read is L2-hot)
        const int lane = tid - 256;
        const int fc = lane & 15;
        const int r0 = (lane >> 4) * 8;

        f4v u1r[12];
#pragma unroll
        for (int i = 0; i < 12; ++i)
            u1r[i] = *(const f4v*)(u1s + (r0 + i) * UP + 4 * fc);
#pragma unroll
        for (int j = 0; j < 8; ++j) {
            const f4v c1 = 0.0625f * (u1r[j] + u1r[j + 4])
                         + 0.25f * (u1r[j + 1] + u1r[j + 3])
                         + 0.375f * u1r[j + 2];
            const size_t g = (size_t)(by + r0 + j) * 1024 + bx + 4 * fc;
            const f4v xc = *(const f4v*)(xp + g);
            __builtin_nontemporal_store(xc - c1, (f4v*)(op + 0 * HW + g));
        }
    }
}

extern "C" void kernel_launch(void* const* d_in, const int* in_sizes, int n_in,
                              void* d_out, int out_size, void* d_ws, size_t ws_size,
                              hipStream_t stream)
{
    const float* x = (const float*)d_in[0];
    float* out = (float*)d_out;
    uwt3_kernel<<<dim3(4096), dim3(TB), 0, stream>>>(x, out);
}

// Round 9
// 107.444 us; speedup vs baseline: 1.0018x; 1.0018x over previous
//
#include <hip/hip_runtime.h>

// Fused 3-level B3-spline UWT, fp32. x:(16,1024,1024)->out:(16,4,1024,1024)=[w1,w2,w3,c3].
// 64x64 tile. Phases:
//  1: global -> xs (92x96, XOR-swizzled, coalesced)           barrier
//  2: xs -> F[48] registers (per passA item)                  barrier
//  3: horizontal a-trous cascade h1->h2->h3 in F; write u1/u2/u3 into an LDS
//     arena ALIASED over the dead xs (62.7 KB total -> 2 blocks/CU)  barrier
//  4: waves 0-3: vertical 5/13/29-tap from u1/u2/u3 -> w2,w3,c3 (4-row strips)
//     waves 4-5: vertical 5-tap from u1 + x re-read -> w1 (8-row strips)
// u pitch 68 floats (17 f4-slots, 17 mod 8 = 1) -> uniform bank quartets for
// both the strided phase-3 writes and the phase-4 strip reads.

typedef float f4v __attribute__((ext_vector_type(4)));

constexpr int TB   = 384;
constexpr int TCOL = 64;
constexpr int TROW = 64;
constexpr int VH   = 14;          // vertical halo
constexpr int XR   = 92;
constexpr int XP   = 96;          // xs pitch (floats)
constexpr int UP   = 68;          // u pitch (floats)
constexpr int U1R  = 68;          // u1 rows: frame [12,80)
constexpr int U2R  = 76;          // u2 rows: frame [8,84)
constexpr int U3R  = 92;          // u3 rows: frame [0,92)
constexpr int ARENA = (U1R + U2R + U3R) * UP;   // 16048 floats = 62.7 KB
constexpr int HW   = 1024 * 1024;

__device__ constexpr float K13[13] = {
    1.f/256, 4.f/256, 10.f/256, 20.f/256, 31.f/256, 40.f/256, 44.f/256,
    40.f/256, 31.f/256, 20.f/256, 10.f/256, 4.f/256, 1.f/256};
__device__ constexpr float K29[29] = {
    1.f/4096,   4.f/4096,  10.f/4096,  20.f/4096,  35.f/4096,  56.f/4096,
    84.f/4096, 120.f/4096, 161.f/4096, 204.f/4096, 246.f/4096, 284.f/4096,
    315.f/4096, 336.f/4096, 344.f/4096, 336.f/4096, 315.f/4096, 284.f/4096,
    246.f/4096, 204.f/4096, 161.f/4096, 120.f/4096,  84.f/4096,  56.f/4096,
    35.f/4096,  20.f/4096,  10.f/4096,   4.f/4096,   1.f/4096};

__device__ __forceinline__ int refl(int i) {
    return i < 0 ? -i : (i >= 1024 ? 2046 - i : i);
}
// xs: row-major, f4-granular XOR swizzle (uniform banks for row-span reads).
__device__ __forceinline__ int xidx(int r, int c4) { return r * XP + 4 * (c4 ^ (r & 7)); }

__global__ __launch_bounds__(TB, 3)
void uwt3_kernel(const float* __restrict__ x, float* __restrict__ out)
{
    __shared__ float lds[ARENA];
    float* xs  = lds;                         // phases 1-2 (8832 floats)
    float* u1s = lds;                         // phases 3-4, aliases xs
    float* u2s = lds + U1R * UP;
    float* u3s = lds + (U1R + U2R) * UP;

    const int tid = threadIdx.x;

    // bijective XCD chunk swizzle (4096 % 8 == 0)
    const int flat = blockIdx.x;
    const int swz  = (flat & 7) * 512 + (flat >> 3);
    const int bxi = swz & 15;
    const int byi = (swz >> 4) & 15;
    const int bz  = swz >> 8;
    const int bx = bxi * TCOL;
    const int by = byi * TROW;

    const float* xp = x + (size_t)bz * HW;
    float* op = out + (size_t)bz * 4 * HW;

    // ---- phase 1: stage x tile rows [by-14,by+78), cols [bx-16,bx+80) ----
    if (bxi != 0 && bxi != 15) {
        for (int e = tid; e < XR * 24; e += TB) {
            const int r = e / 24, m = e - r * 24;
            const int gr = refl(by - VH + r);
            const f4v v = *(const f4v*)(xp + (size_t)gr * 1024 + (bx - 16 + 4 * m));
            *(f4v*)(xs + xidx(r, m)) = v;
        }
    } else {
        for (int e = tid; e < XR * 96; e += TB) {
            const int r = e / 96, c = e - r * 96;
            const int gr = refl(by - VH + r);
            const int gc = refl(bx - 16 + c);
            xs[xidx(r, c >> 2) + (c & 3)] = xp[(size_t)gr * 1024 + gc];
        }
    }
    __syncthreads();

    // ---- phase 2: xs -> registers (all reads complete before aliasing) ----
    const int gi = tid & 3;          // 16-col group
    const int rp = tid >> 2;         // tile-frame row
    float F[48];
    if (tid < XR * 4) {
#pragma unroll
        for (int m = 0; m < 12; ++m)
            *(f4v*)&F[4 * m] = *(const f4v*)(xs + xidx(rp, 4 * gi + m));
    }
    __syncthreads();

    // ---- phase 3: horizontal cascade, write u1/u2/u3 over dead xs ----
    if (tid < XR * 4) {
        // h1 (d=1): F[i] <- h1 @ x-col i+2
#pragma unroll
        for (int i = 2; i < 42; ++i)
            F[i] = 0.0625f * (F[i] + F[i + 4]) + 0.25f * (F[i + 1] + F[i + 3])
                 + 0.375f * F[i + 2];
        if (rp >= 12 && rp < 80) {          // u1 = h1 center, F[14..30)
            float* d = u1s + (rp - 12) * UP + 16 * gi;
#pragma unroll
            for (int k = 0; k < 4; ++k) {
                const f4v v = {F[14 + 4*k], F[15 + 4*k], F[16 + 4*k], F[17 + 4*k]};
                *(f4v*)(d + 4 * k) = v;
            }
        }
        // h2 (d=2): F[i] <- h2 @ x-col i+6
#pragma unroll
        for (int i = 2; i < 34; ++i)
            F[i] = 0.0625f * (F[i] + F[i + 8]) + 0.25f * (F[i + 2] + F[i + 6])
                 + 0.375f * F[i + 4];
        if (rp >= 8 && rp < 84) {           // u2 = h2 center, F[10..26)
            float* d = u2s + (rp - 8) * UP + 16 * gi;
#pragma unroll
            for (int k = 0; k < 4; ++k) {
                const f4v v = {F[10 + 4*k], F[11 + 4*k], F[12 + 4*k], F[13 + 4*k]};
                *(f4v*)(d + 4 * k) = v;
            }
        }
        // h3 (d=4): F[i] <- h3 @ x-col i+14
#pragma unroll
        for (int i = 2; i < 18; ++i)
            F[i] = 0.0625f * (F[i] + F[i + 16]) + 0.25f * (F[i + 4] + F[i + 12])
                 + 0.375f * F[i + 8];
        {                                   // u3 = h3, F[2..18), all rows
            float* d = u3s + rp * UP + 16 * gi;
#pragma unroll
            for (int k = 0; k < 4; ++k) {
                const f4v v = {F[2 + 4*k], F[3 + 4*k], F[4 + 4*k], F[5 + 4*k]};
                *(f4v*)(d + 4 * k) = v;
            }
        }
    }
    __syncthreads();

    // ---- phase 4: vertical convs + outputs ----
    if (tid < 256) {
        // waves 0-3: w2, w3, c3 on 4-row strips
        const int fc = tid & 15;
        const int r0 = (tid >> 4) * 4;
        const size_t gbase = (size_t)(by + r0) * 1024 + bx + 4 * fc;

        // c1 = V1 u1 (5-tap)
        f4v u1r[8];
#pragma unroll
        for (int i = 0; i < 8; ++i)
            u1r[i] = *(const f4v*)(u1s + (r0 + i) * UP + 4 * fc);
        f4v c1[4];
#pragma unroll
        for (int j = 0; j < 4; ++j)
            c1[j] = 0.0625f * (u1r[j] + u1r[j + 4]) + 0.25f * (u1r[j + 1] + u1r[j + 3])
                  + 0.375f * u1r[j + 2];

        // c2 = V2 u2 (13-tap)
        f4v c2[4] = {{0,0,0,0},{0,0,0,0},{0,0,0,0},{0,0,0,0}};
#pragma unroll
        for (int i = 0; i < 16; ++i) {
            const f4v v = *(const f4v*)(u2s + (r0 + i) * UP + 4 * fc);
#pragma unroll
            for (int j = 0; j < 4; ++j) {
                const int m = i - j;
                if (m >= 0 && m <= 12) c2[j] += K13[m] * v;
            }
        }
#pragma unroll
        for (int j = 0; j < 4; ++j)
            __builtin_nontemporal_store(c1[j] - c2[j],
                (f4v*)(op + 1 * HW + gbase + (size_t)j * 1024));

        // c3 = V3 u3 (29-tap)
        f4v c3[4] = {{0,0,0,0},{0,0,0,0},{0,0,0,0},{0,0,0,0}};
#pragma unroll
        for (int i = 0; i < 32; ++i) {
            const f4v v = *(const f4v*)(u3s + (r0 + i) * UP + 4 * fc);
#pragma unroll
            for (int j = 0; j < 4; ++j) {
                const int m = i - j;
                if (m >= 0 && m <= 28) c3[j] += K29[m] * v;
            }
        }
#pragma unroll
        for (int j = 0; j < 4; ++j) {
            __builtin_nontemporal_store(c2[j] - c3[j],
                (f4v*)(op + 2 * HW + gbase + (size_t)j * 1024));
            __builtin_nontemporal_store(c3[j],
                (f4v*)(op + 3 * HW + gbase + (size_t)j * 1024));
        }
    } else {
        // waves 4-5: w1 = x - V1 u1 on 8-row strips (x re-read is L2-hot)
        const int lane = tid - 256;
        const int fc = lane & 15;
        const int r0 = (lane >> 4) * 8;

        f4v u1r[12];
#pragma unroll
        for (int i = 0; i < 12; ++i)
            u1r[i] = *(const f4v*)(u1s + (r0 + i) * UP + 4 * fc);
#pragma unroll
        for (int j = 0; j < 8; ++j) {
            const f4v c1 = 0.0625f * (u1r[j] + u1r[j + 4])
                         + 0.25f * (u1r[j + 1] + u1r[j + 3])
                         + 0.375f * u1r[j + 2];
            const size_t g = (size_t)(by + r0 + j) * 1024 + bx + 4 * fc;
            const f4v xc = *(const f4v*)(xp + g);
            __builtin_nontemporal_store(xc - c1, (f4v*)(op + 0 * HW + g));
        }
    }
}

extern "C" void kernel_launch(void* const* d_in, const int* in_sizes, int n_in,
                              void* d_out, int out_size, void* d_ws, size_t ws_size,
                              hipStream_t stream)
{
    const float* x = (const float*)d_in[0];
    float* out = (float*)d_out;
    uwt3_kernel<<<dim3(4096), dim3(TB), 0, stream>>>(x, out);
}

// Round 10
// 79.812 us; speedup vs baseline: 1.3486x; 1.3462x over previous
//
#include <hip/hip_runtime.h>
#include <stdint.h>

// Fused 3-level B3-spline UWT, fp32 in/out. x:(16,1024,1024)->out:(16,4,1024,1024).
// 64x64 tile, 2 barriers, 53.76 KB LDS -> 3 blocks/CU (12 waves).
//  stage:  global -> xs (92x96 f32, f4-XOR swizzle), reflect-aware f4 path
//  passA:  per (row,16-col group): horizontal a-trous cascade h1->h2->h3 in a
//          48-float register buffer; u1,u2 -> bf16 tiles (pair-XOR swizzled);
//          u3 -> IN-PLACE over xs (same-row ownership => race-free)
//  passB:  vertical 5/13/29-tap dense convs; w1 uses global x re-read (L2-hot)

typedef float f4v __attribute__((ext_vector_type(4)));

constexpr int TB  = 256;
constexpr int VH  = 14;
constexpr int XR  = 92;
constexpr int XP  = 96;     // xs pitch (floats)
constexpr int U1P = 32;     // u1 pitch (dwords), rows = frame [12,80)
constexpr int U1R = 68;
constexpr int U2P = 32;     // u2 pitch (dwords), rows = frame [8,84)
constexpr int U2R = 76;
constexpr int HW  = 1024 * 1024;

__device__ constexpr float K13[13] = {
    1.f/256, 4.f/256, 10.f/256, 20.f/256, 31.f/256, 40.f/256, 44.f/256,
    40.f/256, 31.f/256, 20.f/256, 10.f/256, 4.f/256, 1.f/256};
__device__ constexpr float K29[29] = {
    1.f/4096,   4.f/4096,  10.f/4096,  20.f/4096,  35.f/4096,  56.f/4096,
    84.f/4096, 120.f/4096, 161.f/4096, 204.f/4096, 246.f/4096, 284.f/4096,
    315.f/4096, 336.f/4096, 344.f/4096, 336.f/4096, 315.f/4096, 284.f/4096,
    246.f/4096, 204.f/4096, 161.f/4096, 120.f/4096,  84.f/4096,  56.f/4096,
    35.f/4096,  20.f/4096,  10.f/4096,   4.f/4096,   1.f/4096};

__device__ __forceinline__ int refl(int i) {
    return i < 0 ? -i : (i >= 1024 ? 2046 - i : i);
}
// xs: f4-granular XOR swizzle (uniform bank quartets for all access shapes used)
__device__ __forceinline__ int xidx(int r, int c4) { return r * XP + 4 * (c4 ^ (r & 7)); }

// bf16 pack (round-half-up) / unpack (lo = element 0)
__device__ __forceinline__ uint32_t pk(float a, float b) {
    return ((__builtin_bit_cast(uint32_t, a) + 0x8000u) >> 16)
         | ((__builtin_bit_cast(uint32_t, b) + 0x8000u) & 0xFFFF0000u);
}
__device__ __forceinline__ float ulo(uint32_t w) { return __builtin_bit_cast(float, w << 16); }
__device__ __forceinline__ float uhi(uint32_t w) { return __builtin_bit_cast(float, w & 0xFFFF0000u); }

__global__ __launch_bounds__(TB, 3)
void uwt3_kernel(const float* __restrict__ x, float* __restrict__ out)
{
    __shared__ __align__(16) uint32_t ldsw[XR * XP + U1R * U1P + U2R * U2P]; // 13440 dw
    float*    xs  = (float*)ldsw;                 // stage + (after passA) u3
    uint32_t* u1b = ldsw + XR * XP;
    uint32_t* u2b = ldsw + XR * XP + U1R * U1P;

    const int tid = threadIdx.x;

    // bijective XCD chunk swizzle (4096 % 8 == 0)
    const int flat = blockIdx.x;
    const int swz  = (flat & 7) * 512 + (flat >> 3);
    const int bxi = swz & 15;
    const int byi = (swz >> 4) & 15;
    const int bz  = swz >> 8;
    const int bx = bxi * 64;
    const int by = byi * 64;

    const float* xp = x + (size_t)bz * HW;
    float* op = out + (size_t)bz * 4 * HW;

    // ---- stage x tile rows [by-14,by+78), cols [bx-16,bx+80) ----
    for (int e = tid; e < XR * 24; e += TB) {
        const int r = e / 24, m = e - r * 24;
        const int gr = refl(by - VH + r);
        const int gc0 = bx - 16 + 4 * m;
        f4v v;
        if (gc0 >= 0 && gc0 <= 1020) {
            v = *(const f4v*)(xp + (size_t)gr * 1024 + gc0);
        } else {
#pragma unroll
            for (int q = 0; q < 4; ++q) v[q] = xp[(size_t)gr * 1024 + refl(gc0 + q)];
        }
        *(f4v*)(xs + xidx(r, m)) = v;
    }
    __syncthreads();

    // ---- passA: horizontal cascade; u1/u2 -> bf16 tiles; u3 in-place over xs ----
    for (int t = tid; t < XR * 4; t += TB) {
        const int gi = t & 3;
        const int rp = t >> 2;
        float F[48];
#pragma unroll
        for (int m = 0; m < 12; ++m)
            *(f4v*)&F[4 * m] = *(const f4v*)(xs + xidx(rp, 4 * gi + m));
        // h1 (d=1): F[i] <- h1 @ x-frame col i+2
#pragma unroll
        for (int i = 2; i < 42; ++i)
            F[i] = 0.0625f * (F[i] + F[i + 4]) + 0.25f * (F[i + 1] + F[i + 3])
                 + 0.375f * F[i + 2];
        if (rp >= 12 && rp < 80) {     // u1 = h1 center (tile cols 16gi..+16) = F[14..30)
            const int ur = rp - 12, key = ur & 15;
            uint32_t* d = u1b + ur * U1P;
#pragma unroll
            for (int j = 0; j < 4; ++j) {
                uint2 w;
                w.x = pk(F[14 + 4*j], F[15 + 4*j]);
                w.y = pk(F[16 + 4*j], F[17 + 4*j]);
                *(uint2*)(d + 2 * ((4 * gi + j) ^ key)) = w;
            }
        }
        // h2 (d=2): F[i] <- h2 @ x-frame col i+6
#pragma unroll
        for (int i = 2; i < 34; ++i)
            F[i] = 0.0625f * (F[i] + F[i + 8]) + 0.25f * (F[i + 2] + F[i + 6])
                 + 0.375f * F[i + 4];
        if (rp >= 8 && rp < 84) {      // u2 = h2 center = F[10..26)
            const int ur = rp - 8, key = ur & 15;
            uint32_t* d = u2b + ur * U2P;
#pragma unroll
            for (int j = 0; j < 4; ++j) {
                uint2 w;
                w.x = pk(F[10 + 4*j], F[11 + 4*j]);
                w.y = pk(F[12 + 4*j], F[13 + 4*j]);
                *(uint2*)(d + 2 * ((4 * gi + j) ^ key)) = w;
            }
        }
        // h3 (d=4): F[i] <- h3 @ x-frame col i+14
#pragma unroll
        for (int i = 2; i < 18; ++i)
            F[i] = 0.0625f * (F[i] + F[i + 16]) + 0.25f * (F[i + 4] + F[i + 12])
                 + 0.375f * F[i + 8];
        // u3 = h3 center = F[2..18) -> xs row rp (only this item's row: race-free)
#pragma unroll
        for (int q = 0; q < 4; ++q) {
            const f4v v = {F[2 + 4*q], F[3 + 4*q], F[4 + 4*q], F[5 + 4*q]};
            *(f4v*)(xs + xidx(rp, 4 + 4 * gi + q)) = v;
        }
    }
    __syncthreads();

    // ---- passB: vertical convs + all 4 outputs; thread = (f4-col, 4-row strip) ----
    const int fc = tid & 15;
    const int r0 = (tid >> 4) * 4;
    const size_t gbase = (size_t)(by + r0) * 1024 + bx + 4 * fc;

    // c1 = V1 u1 (5-tap, bf16 source)
    f4v c1[4];
    {
        f4v u1r[8];
#pragma unroll
        for (int i = 0; i < 8; ++i) {
            const int rr = r0 + i;
            const uint2 w = *(const uint2*)(u1b + rr * U1P + 2 * (fc ^ (rr & 15)));
            u1r[i] = f4v{ulo(w.x), uhi(w.x), ulo(w.y), uhi(w.y)};
        }
#pragma unroll
        for (int j = 0; j < 4; ++j)
            c1[j] = 0.0625f * (u1r[j] + u1r[j + 4]) + 0.25f * (u1r[j + 1] + u1r[j + 3])
                  + 0.375f * u1r[j + 2];
    }
    // w1 = x - c1 (x re-read from global, L2/L3-hot)
#pragma unroll
    for (int j = 0; j < 4; ++j) {
        const f4v xc = *(const f4v*)(xp + gbase + (size_t)j * 1024);
        __builtin_nontemporal_store(xc - c1[j], (f4v*)(op + 0 * HW + gbase + (size_t)j * 1024));
    }

    // c2 = V2 u2 (13-tap dense, bf16 source)
    f4v c2[4] = {{0,0,0,0},{0,0,0,0},{0,0,0,0},{0,0,0,0}};
#pragma unroll
    for (int i = 0; i < 16; ++i) {
        const int rr = r0 + i;
        const uint2 w = *(const uint2*)(u2b + rr * U2P + 2 * (fc ^ (rr & 15)));
        const f4v v = f4v{ulo(w.x), uhi(w.x), ulo(w.y), uhi(w.y)};
#pragma unroll
        for (int j = 0; j < 4; ++j) {
            const int m = i - j;
            if (m >= 0 && m <= 12) c2[j] += K13[m] * v;
        }
    }
#pragma unroll
    for (int j = 0; j < 4; ++j)
        __builtin_nontemporal_store(c1[j] - c2[j], (f4v*)(op + 1 * HW + gbase + (size_t)j * 1024));

    // c3 = V3 u3 (29-tap dense, u3 lives in xs arena)
    f4v c3[4] = {{0,0,0,0},{0,0,0,0},{0,0,0,0},{0,0,0,0}};
#pragma unroll
    for (int i = 0; i < 32; ++i) {
        const int rr = r0 + i;
        const f4v v = *(const f4v*)(xs + xidx(rr, 4 + fc));
#pragma unroll
        for (int j = 0; j < 4; ++j) {
            const int m = i - j;
            if (m >= 0 && m <= 28) c3[j] += K29[m] * v;
        }
    }
#pragma unroll
    for (int j = 0; j < 4; ++j) {
        __builtin_nontemporal_store(c2[j] - c3[j], (f4v*)(op + 2 * HW + gbase + (size_t)j * 1024));
        __builtin_nontemporal_store(c3[j],        (f4v*)(op + 3 * HW + gbase + (size_t)j * 1024));
    }
}

extern "C" void kernel_launch(void* const* d_in, const int* in_sizes, int n_in,
                              void* d_out, int out_size, void* d_ws, size_t ws_size,
                              hipStream_t stream)
{
    const float* x = (const float*)d_in[0];
    float* out = (float*)d_out;
    uwt3_kernel<<<dim3(4096), dim3(TB), 0, stream>>>(x, out);
}